// Round 10
// baseline (211.370 us; speedup 1.0000x reference)
//
#include <hip/hip_runtime.h>

// DCNv4 on gfx950 — bf16 MFMA pipeline, fragment-swizzled operands.
// R17: R16 with the OOB bug fixed. R16's sampler unpack wrote arr[28..31]
//  into float arr[28] (guard `idx<27` dropped when switching to packed u32
//  unpack) -> UB -> absmax 3.2e-2. Fix: arr[32] (entries 27..31 DCE'd).
//  R16 changes carried forward unchanged:
//  1) oms sampler: packed f32x2 channel math (u32 lshl/and unpack +
//     v_pk_fma_f32) — ~20% VALU cut on the throughput-limited sampler.
//  2) K4 rewrite: full op_wF (128 KB) in LDS, block=1024, M=128, B via
//     conflict-free ds_read_b128, 8 global A-loads per wave (old: 72
//     global loads per 64 MFMA, unstaged).
// KW: vp/op frag-swizzle + per-g padded om_wG
// KF: dwconv3x3 + value GEMM (block = image row) -> xdwF, value_g
// OMS: om GEMM (B in regs) -> s_om -> 2-px packed sampling -> sampledF
// K4: out = sampledF @ op_wF (M=128, B in LDS, fp32 NHWC out)

typedef __bf16 bf16_t;
typedef bf16_t bf16x8 __attribute__((ext_vector_type(8)));
typedef bf16_t bf16x4 __attribute__((ext_vector_type(4)));
typedef float f32x4 __attribute__((ext_vector_type(4)));
typedef float f32x2 __attribute__((ext_vector_type(2)));
typedef unsigned int u32x4 __attribute__((ext_vector_type(4)));

namespace {
constexpr int NN = 8, HH = 64, WW = 64, CC = 256;
constexpr int G = 32, GC = 8;
constexpr int NPIX = NN * HH * WW;            // 32768
}

// fragment-swizzled flat index for a [rows][256] bf16 matrix
__device__ __forceinline__ size_t fragIdx(int row, int c) {
  return ((size_t)(row >> 4) * 4096) + ((c >> 5) * 512) + (((c >> 3) & 3) * 128) +
         ((row & 15) * 8) + (c & 7);
}

__device__ __forceinline__ float bf2f_lo(unsigned u) {
  return __builtin_bit_cast(float, u << 16);
}
__device__ __forceinline__ float bf2f_hi(unsigned u) {
  return __builtin_bit_cast(float, u & 0xffff0000u);
}

// ---------------- KW: weights -> bf16 fragment layouts ----------------------
// b<16: vp_w  b<32: op_w  (64x64 LDS transpose, as before)
// b>=32: om_wG[g] = per-g fragment matrix [32 rows(j, 27 real)][256 cols(c)]
__global__ __launch_bounds__(256) void convert_weights_kernel(
    const float* __restrict__ om_w, const float* __restrict__ vp_w,
    const float* __restrict__ op_w, bf16_t* __restrict__ om_wG,
    bf16_t* __restrict__ vp_wF, bf16_t* __restrict__ op_wF) {
  __shared__ float s_t[64][65];
  __shared__ float s_w[256][27];
  const int b = blockIdx.x, t = threadIdx.x;
  if (b < 32) {
    const float* src;
    bf16_t* dst;
    int kt, nt;
    if (b < 16) { src = vp_w; dst = vp_wF; kt = b >> 2; nt = b & 3; }
    else        { src = op_w; dst = op_wF; kt = (b - 16) >> 2; nt = (b - 16) & 3; }
    const int nl = t & 63, kh = t >> 6;
    const int n = nt * 64 + nl;
#pragma unroll
    for (int i = 0; i < 16; ++i) {
      const int kl = kh * 16 + i;
      s_t[kl][nl] = src[(size_t)(kt * 64 + kl) * CC + n];
    }
    __syncthreads();
    const int lane = t & 63, kq = lane >> 4, n15 = lane & 15, n16 = t >> 6;
#pragma unroll
    for (int it = 0; it < 2; ++it) {
      bf16x8 v;
#pragma unroll
      for (int j = 0; j < 8; ++j)
        v[j] = (bf16_t)s_t[it * 32 + kq * 8 + j][n16 * 16 + n15];
      const size_t off = (size_t)(nt * 4 + n16) * 4096 + (size_t)(kt * 2 + it) * 512 +
                         kq * 128 + n15 * 8;
      *(bf16x8*)(dst + off) = v;
    }
  } else {
    const int g = b - 32;
    // transpose load: s_w[c][j] = om_w[c][g*27+j]
#pragma unroll
    for (int j = 0; j < 27; ++j) s_w[t][j] = om_w[(size_t)t * 864 + g * 27 + j];
    __syncthreads();
#pragma unroll
    for (int i = 0; i < 4; ++i) {
      const int chunk = i * 256 + t;  // 1024 chunks of 8 bf16
      const int tile = chunk >> 9, ks = (chunk >> 6) & 7, kq = (chunk >> 4) & 3,
                n15 = chunk & 15;
      const int j = tile * 16 + n15;
      bf16x8 v;
#pragma unroll
      for (int cl = 0; cl < 8; ++cl) {
        const int c = ks * 32 + kq * 8 + cl;
        v[cl] = (j < 27) ? (bf16_t)s_w[c][j] : (bf16_t)0.0f;
      }
      *(bf16x8*)(om_wG + ((size_t)g << 13) + (size_t)chunk * 8) = v;
    }
  }
}

// ---------------- KF: fused dwconv3x3 + value GEMM; block = one image row ----
__global__ __launch_bounds__(512, 4) void dwconv_value_kernel(
    const float* __restrict__ x, const float* __restrict__ dw_w,
    const float* __restrict__ dw_b, const bf16_t* __restrict__ vp_wF,
    const float* __restrict__ vp_b, bf16_t* __restrict__ xdwF,
    bf16_t* __restrict__ value_g) {
  __shared__ bf16_t s_xf[64 * 256];  // x bf16 fragments for this row's 4 m-tiles

  const int t = threadIdx.x;
  const int row = blockIdx.x;        // img*64 + y
  const int y = row & 63;
  const int img = row >> 6;

  // ---- Phase A: dwconv
  {
    const int cq = (t & 63) * 4;   // channel base
    const int seg = t >> 6;        // 8-px segment
    const bool up = (y > 0), dn = (y < HH - 1);
    const float* xrow = x + (size_t)row * WW * CC + cq;

    const float4 bias = *(const float4*)&dw_b[cq];
    float4 dw[9];
#pragma unroll
    for (int i = 0; i < 9; ++i) dw[i] = *(const float4*)&dw_w[(size_t)i * CC + cq];

    const float4 zero = make_float4(0.f, 0.f, 0.f, 0.f);
    auto loadcol = [&](int xx, float4 c[3]) {
      if (xx < 0 || xx >= WW) { c[0] = c[1] = c[2] = zero; return; }
      c[0] = up ? *(const float4*)(xrow + ((size_t)xx - WW) * CC) : zero;
      c[1] = *(const float4*)(xrow + (size_t)xx * CC);
      c[2] = dn ? *(const float4*)(xrow + ((size_t)xx + WW) * CC) : zero;
    };

    const int x0 = seg * 8;
    float4 cm[3], cc[3], cp[3];
    loadcol(x0 - 1, cm);
    loadcol(x0, cc);

    for (int xx = x0; xx < x0 + 8; ++xx) {
      loadcol(xx + 1, cp);
      float4 a = bias;
#pragma unroll
      for (int r = 0; r < 3; ++r) {
        const float4 w0 = dw[r * 3 + 0], w1 = dw[r * 3 + 1], w2 = dw[r * 3 + 2];
        a.x = fmaf(cm[r].x, w0.x, fmaf(cc[r].x, w1.x, fmaf(cp[r].x, w2.x, a.x)));
        a.y = fmaf(cm[r].y, w0.y, fmaf(cc[r].y, w1.y, fmaf(cp[r].y, w2.y, a.y)));
        a.z = fmaf(cm[r].z, w0.z, fmaf(cc[r].z, w1.z, fmaf(cp[r].z, w2.z, a.z)));
        a.w = fmaf(cm[r].w, w0.w, fmaf(cc[r].w, w1.w, fmaf(cp[r].w, w2.w, a.w)));
      }
      const int pix = row * WW + xx;
      bf16x4 av, cv;
      av[0] = (bf16_t)a.x; av[1] = (bf16_t)a.y; av[2] = (bf16_t)a.z; av[3] = (bf16_t)a.w;
      cv[0] = (bf16_t)cc[1].x; cv[1] = (bf16_t)cc[1].y;
      cv[2] = (bf16_t)cc[1].z; cv[3] = (bf16_t)cc[1].w;
      *(bf16x4*)&xdwF[fragIdx(pix, cq)] = av;
      const int lf = (xx >> 4) * 4096 + ((cq >> 5) * 512) + (((cq >> 3) & 3) * 128) +
                     ((xx & 15) * 8) + (cq & 7);
      *(bf16x4*)&s_xf[lf] = cv;
#pragma unroll
      for (int r = 0; r < 3; ++r) { cm[r] = cc[r]; cc[r] = cp[r]; }
    }
  }
  __syncthreads();

  // ---- Phase B: value GEMM (M=64 from LDS, N=256)
  {
    const int lane = t & 63;
    const int wave = t >> 6;
    const int mq = wave >> 1;      // m-tile 0..3
    const int nh = wave & 1;       // n-half
    const int m = lane & 15;
    const int kq = lane >> 4;

    const bf16_t* Ap = s_xf + mq * 4096 + lane * 8;
    const bf16_t* Bp = vp_wF + (size_t)(nh * 8) * 4096 + lane * 8;

    f32x4 acc[8] = {};
#pragma unroll
    for (int ks = 0; ks < 8; ++ks) {
      const bf16x8 a = *(const bf16x8*)(Ap + ks * 512);
#pragma unroll
      for (int i = 0; i < 8; ++i) {
        const bf16x8 b = *(const bf16x8*)(Bp + (size_t)i * 4096 + ks * 512);
        acc[i] = __builtin_amdgcn_mfma_f32_16x16x32_bf16(a, b, acc[i], 0, 0, 0);
      }
    }

#pragma unroll
    for (int i = 0; i < 8; ++i) {
      const int n = (nh * 8 + i) * 16 + m;
      const float bs = vp_b[n];
      const int g = n >> 3, c = n & 7;
      bf16_t* plane = value_g + ((size_t)(img * G + g) << 15) + c;
#pragma unroll
      for (int r = 0; r < 4; ++r) {
        const int pl = mq * 16 + kq * 4 + r;           // pixel local 0..63
        const int pin = y * 64 + pl;                   // pixel within image
        plane[(size_t)pin * GC] = (bf16_t)(acc[i][r] + bs);
      }
    }
  }
}

// ---------------- OMS: fused om GEMM + sampling; block = (img, g, quarter) --
// grid b: img = b&7, g = (b>>3)&31, quarter = b>>8  (R9-proven config).
// Block = 512 threads = 8 waves; each wave owns 8 m-tiles (128 px).
// LDS 135.2 KB -> 1 block/CU. Sampling: 2 px/thread, packed f32x2 math.
__global__ __launch_bounds__(512, 2) void oms_kernel(
    const bf16_t* __restrict__ xdwF, const bf16_t* __restrict__ om_wG,
    const float* __restrict__ om_b, const bf16_t* __restrict__ value_g,
    bf16_t* __restrict__ sampledF) {
  __shared__ bf16x8 s_v[66 * 66];          // 69,696 B zero-padded value plane
  __shared__ bf16_t s_om[8][4][128][8];    // 65,536 B chunk-major, p-stride 16B

  const int t = threadIdx.x;
  const int lane = t & 63, wave = t >> 6;  // wave 0..7
  const int b = blockIdx.x;
  const int img = b & 7, g = (b >> 3) & 31, quarter = b >> 8;
  const int c15 = lane & 15, kq = lane >> 4;
  const int tile0 = img * 256 + quarter * 64;   // global 16-px-tile base

  // ---- B-frags (g's padded 32 om columns) into registers
  bf16x8 wf[2][8];
  {
    const bf16_t* base = om_wG + ((size_t)g << 13) + (size_t)lane * 8;
#pragma unroll
    for (int n2 = 0; n2 < 2; ++n2)
#pragma unroll
      for (int ks = 0; ks < 8; ++ks)
        wf[n2][ks] = *(const bf16x8*)(base + n2 * 4096 + ks * 512);
  }
  float bias[2][4];
#pragma unroll
  for (int n2 = 0; n2 < 2; ++n2)
#pragma unroll
    for (int r = 0; r < 4; ++r) {
      const int j = n2 * 16 + kq * 4 + r;
      bias[n2][r] = (j < 27) ? om_b[g * 27 + j] : 0.0f;
    }

  // ---- stage full value plane: zero border + interior
  {
    const bf16x8 zv = {};
    for (int i = t; i < 260; i += 512) {
      int Y, X;
      if (i < 66)       { Y = 0;           X = i; }
      else if (i < 132) { Y = 65;          X = i - 66; }
      else if (i < 196) { Y = i - 132 + 1; X = 0; }
      else              { Y = i - 196 + 1; X = 65; }
      s_v[Y * 66 + X] = zv;
    }
    const bf16x8* plane = (const bf16x8*)(value_g + ((size_t)(img * G + g) << 15));
#pragma unroll
    for (int i = 0; i < 8; ++i) {
      const int c = i * 512 + t;   // 0..4095
      s_v[((c >> 6) + 1) * 66 + (c & 63) + 1] = plane[c];
    }
  }

  // ---- om GEMM: 8 tiles/wave -> s_om[wave] (D[j][px], bf16, chunk-major)
  {
    const int tb = tile0 + wave * 8;
#pragma unroll
    for (int q = 0; q < 8; ++q) {
      const bf16_t* Ap = xdwF + ((size_t)(tb + q)) * 4096 + (size_t)lane * 8;
      f32x4 a0 = {}, a1 = {};
#pragma unroll
      for (int ks = 0; ks < 8; ++ks) {
        const bf16x8 xf = *(const bf16x8*)(Ap + ks * 512);
        a0 = __builtin_amdgcn_mfma_f32_16x16x32_bf16(wf[0][ks], xf, a0, 0, 0, 0);
        a1 = __builtin_amdgcn_mfma_f32_16x16x32_bf16(wf[1][ks], xf, a1, 0, 0, 0);
      }
      // lane holds j = n2*16 + kq*4 + r for pixel p = q*16 + c15 (0..127)
      const int p = q * 16 + c15;
      bf16x4 b0, b1;
#pragma unroll
      for (int r = 0; r < 4; ++r) {
        b0[r] = (bf16_t)(a0[r] + bias[0][r]);
        b1[r] = (bf16_t)(a1[r] + bias[1][r]);
      }
      // chunk = j>>3: n2=0 -> kq>>1, n2=1 -> 2+(kq>>1); half = kq&1
      *(bf16x4*)&s_om[wave][kq >> 1][p][(kq & 1) * 4] = b0;
      *(bf16x4*)&s_om[wave][2 + (kq >> 1)][p][(kq & 1) * 4] = b1;
    }
  }
  __syncthreads();   // s_v ready (s_om is same-wave, covered by the barrier too)

  // ---- sampling: 2 px/thread (rows wave*2 and wave*2+1 of the quarter),
  //      interleaved tap chains + packed f32x2 channel math.
  {
    const int pinA = quarter * 1024 + wave * 128 + lane;  // in-image px
    const int pinB = pinA + 64;
    float arrA[32], arrB[32];    // R16 bug: was [28]; unpack writes 0..31
#pragma unroll
    for (int c = 0; c < 4; ++c) {
      const u32x4 oA = *(const u32x4*)&s_om[wave][c][lane][0];
      const u32x4 oB = *(const u32x4*)&s_om[wave][c][64 + lane][0];
#pragma unroll
      for (int h = 0; h < 4; ++h) {
        const int idx = c * 8 + h * 2;
        arrA[idx] = bf2f_lo(oA[h]); arrA[idx + 1] = bf2f_hi(oA[h]);
        arrB[idx] = bf2f_lo(oB[h]); arrB[idx + 1] = bf2f_hi(oB[h]);
      }
    }
    const int xw = lane;             // pin & 63 (wave*128 is 0 mod 64)
    const int yA = (pinA >> 6) & 63;
    const int yB = yA + 1;

    f32x2 accA[4] = {}, accB[4] = {};

    auto tap = [&](const float* arr, const int y, f32x2* acc2, const int k) {
      const float pxf = (float)(xw + (k % 3) - 1) + arr[2 * k];
      const float pyf = (float)(y + (k / 3) - 1) + arr[2 * k + 1];
      const float mk = arr[18 + k];
      const float x0f = floorf(pxf), y0f = floorf(pyf);
      const float tx = pxf - x0f, ty = pyf - y0f;
      const int ix = (int)x0f, iy = (int)y0f;

      // clamp to padded range [-1,64]; border zeros kill OOB contributions
      const int iX0 = min(max(ix, -1), 64) + 1;
      const int iX1 = min(max(ix + 1, -1), 64) + 1;
      const int iY0 = min(max(iy, -1), 64) + 1;
      const int iY1 = min(max(iy + 1, -1), 64) + 1;

      const u32x4 c00 = *(const u32x4*)&s_v[iY0 * 66 + iX0];
      const u32x4 c01 = *(const u32x4*)&s_v[iY0 * 66 + iX1];
      const u32x4 c10 = *(const u32x4*)&s_v[iY1 * 66 + iX0];
      const u32x4 c11 = *(const u32x4*)&s_v[iY1 * 66 + iX1];

      const float w00 = mk * (1.0f - ty) * (1.0f - tx);
      const float w01 = mk * (1.0f - ty) * tx;
      const float w10 = mk * ty * (1.0f - tx);
      const float w11 = mk * ty * tx;
      const f32x2 W00 = {w00, w00}, W01 = {w01, w01};
      const f32x2 W10 = {w10, w10}, W11 = {w11, w11};

#pragma unroll
      for (int pr = 0; pr < 4; ++pr) {
        f32x2 v;
        v[0] = bf2f_lo(c00[pr]); v[1] = bf2f_hi(c00[pr]);
        acc2[pr] = __builtin_elementwise_fma(W00, v, acc2[pr]);
        v[0] = bf2f_lo(c01[pr]); v[1] = bf2f_hi(c01[pr]);
        acc2[pr] = __builtin_elementwise_fma(W01, v, acc2[pr]);
        v[0] = bf2f_lo(c10[pr]); v[1] = bf2f_hi(c10[pr]);
        acc2[pr] = __builtin_elementwise_fma(W10, v, acc2[pr]);
        v[0] = bf2f_lo(c11[pr]); v[1] = bf2f_hi(c11[pr]);
        acc2[pr] = __builtin_elementwise_fma(W11, v, acc2[pr]);
      }
    };

#pragma unroll
    for (int k = 0; k < 9; ++k) {
      tap(arrA, yA, accA, k);
      tap(arrB, yB, accB, k);
    }

    bf16x8 svA, svB;
#pragma unroll
    for (int pr = 0; pr < 4; ++pr) {
      svA[2 * pr] = (bf16_t)accA[pr][0];
      svA[2 * pr + 1] = (bf16_t)accA[pr][1];
      svB[2 * pr] = (bf16_t)accB[pr][0];
      svB[2 * pr + 1] = (bf16_t)accB[pr][1];
    }
    *(bf16x8*)(sampledF + fragIdx(img * 4096 + pinA, g * 8)) = svA;
    *(bf16x8*)(sampledF + fragIdx(img * 4096 + pinB, g * 8)) = svB;
  }
}

// ---------------- K4: out = sampledF @ op_wF, M=128/block, B in LDS ----------
// Block = 1024 thr = 16 waves (mq 0..7, nh 0..1); full op_wF (128 KB) staged
// once into LDS; per wave 64 MFMA fed by conflict-free ds_read_b128 + 8
// global A-loads. Grid 256 = 1 block/CU.
__global__ __launch_bounds__(1024, 1) void out_gemm_kernel(
    const bf16_t* __restrict__ AF, const bf16_t* __restrict__ BF,
    float* __restrict__ out) {
  __shared__ bf16_t s_b[CC * CC];  // 131,072 B: full B, frag layout (linear copy)

  const int t = threadIdx.x;
  {
    const bf16x8* src = (const bf16x8*)BF;
    bf16x8* dst = (bf16x8*)s_b;
#pragma unroll
    for (int i = 0; i < 8; ++i) dst[i * 1024 + t] = src[i * 1024 + t];
  }
  __syncthreads();

  const int lane = t & 63;
  const int wave = t >> 6;        // 0..15
  const int mq = wave >> 1;       // m-tile 0..7
  const int nh = wave & 1;        // n-half
  const int mt = blockIdx.x * 8 + mq;
  const int m = lane & 15;
  const int kq = lane >> 4;

  const bf16_t* Ap = AF + (size_t)mt * 4096 + lane * 8;
  const bf16_t* Bp = s_b + (size_t)(nh * 8) * 4096 + lane * 8;

  f32x4 acc[8] = {};
#pragma unroll
  for (int ks = 0; ks < 8; ++ks) {
    const bf16x8 a = *(const bf16x8*)(Ap + ks * 512);
#pragma unroll
    for (int i = 0; i < 8; ++i) {
      const bf16x8 b = *(const bf16x8*)(Bp + (size_t)i * 4096 + ks * 512);
      acc[i] = __builtin_amdgcn_mfma_f32_16x16x32_bf16(a, b, acc[i], 0, 0, 0);
    }
  }

#pragma unroll
  for (int i = 0; i < 8; ++i) {
    const int n = (nh * 8 + i) * 16 + m;
#pragma unroll
    for (int r = 0; r < 4; ++r) {
      const int pix = mt * 16 + kq * 4 + r;
      out[(size_t)pix * CC + n] = acc[i][r];
    }
  }
}

extern "C" void kernel_launch(void* const* d_in, const int* in_sizes, int n_in,
                              void* d_out, int out_size, void* d_ws, size_t ws_size,
                              hipStream_t stream) {
  const float* x = (const float*)d_in[0];
  const float* dw_w = (const float*)d_in[1];
  const float* dw_b = (const float*)d_in[2];
  const float* om_w = (const float*)d_in[3];
  const float* om_b = (const float*)d_in[4];
  const float* vp_w = (const float*)d_in[5];
  const float* vp_b = (const float*)d_in[6];
  const float* op_w = (const float*)d_in[7];
  float* out = (float*)d_out;

  // workspace layout (bytes)
  char* ws = (char*)d_ws;
  bf16_t* value_g = (bf16_t*)ws;                      // 16,777,216
  bf16_t* xdwF = (bf16_t*)(ws + 16777216);            // 16,777,216
  bf16_t* sampledF = (bf16_t*)(ws + 33554432);        // 16,777,216
  bf16_t* om_wG = (bf16_t*)(ws + 50331648);           //    524,288
  bf16_t* vp_wF = (bf16_t*)(ws + 50855936);           //    131,072
  bf16_t* op_wF = (bf16_t*)(ws + 50987008);           //    131,072

  convert_weights_kernel<<<64, 256, 0, stream>>>(om_w, vp_w, op_w,
                                                 om_wG, vp_wF, op_wF);
  dwconv_value_kernel<<<NN * HH, 512, 0, stream>>>(x, dw_w, dw_b, vp_wF, vp_b,
                                                   xdwF, value_g);
  oms_kernel<<<1024, 512, 0, stream>>>(xdwF, om_wG, om_b, value_g, sampledF);
  out_gemm_kernel<<<NPIX / 128, 1024, 0, stream>>>(sampledF, op_wF, out);
}

// Round 12
// 193.842 us; speedup vs baseline: 1.0904x; 1.0904x over previous
//
#include <hip/hip_runtime.h>

// DCNv4 on gfx950 — bf16 MFMA pipeline, fragment-swizzled operands.
// R19: R18 resubmit (container infra failed twice; no counters; same pattern
//  as R13->R14 which ran clean on retry). Source unchanged from R18:
//  - oms sampler reverted byte-for-byte to R15's scalar form (proven 57us).
//    R17's packed f32x2 sampler REGRESSED 57->71us (VALUBusy down with dur
//    up = stalls; elementwise_fma likely not lowering to v_pk_fma_f32).
//    Third packed-math loss to scalar -> scalar cvt+fmaf is final.
//  - K4 LDS-staged rewrite kept (R15->R17 subtraction: KW+KF+K4 146->140us).
// KW: vp/op frag-swizzle + per-g padded om_wG
// KF: dwconv3x3 + value GEMM (block = image row) -> xdwF, value_g
// OMS: om GEMM (B in regs) -> s_om -> 2-px scalar sampling -> sampledF
// K4: out = sampledF @ op_wF (M=128, B in LDS, fp32 NHWC out)

typedef __bf16 bf16_t;
typedef bf16_t bf16x8 __attribute__((ext_vector_type(8)));
typedef bf16_t bf16x4 __attribute__((ext_vector_type(4)));
typedef float f32x4 __attribute__((ext_vector_type(4)));

namespace {
constexpr int NN = 8, HH = 64, WW = 64, CC = 256;
constexpr int G = 32, GC = 8;
constexpr int NPIX = NN * HH * WW;            // 32768
}

// fragment-swizzled flat index for a [rows][256] bf16 matrix
__device__ __forceinline__ size_t fragIdx(int row, int c) {
  return ((size_t)(row >> 4) * 4096) + ((c >> 5) * 512) + (((c >> 3) & 3) * 128) +
         ((row & 15) * 8) + (c & 7);
}

// ---------------- KW: weights -> bf16 fragment layouts ----------------------
// b<16: vp_w  b<32: op_w  (64x64 LDS transpose, as before)
// b>=32: om_wG[g] = per-g fragment matrix [32 rows(j, 27 real)][256 cols(c)]
__global__ __launch_bounds__(256) void convert_weights_kernel(
    const float* __restrict__ om_w, const float* __restrict__ vp_w,
    const float* __restrict__ op_w, bf16_t* __restrict__ om_wG,
    bf16_t* __restrict__ vp_wF, bf16_t* __restrict__ op_wF) {
  __shared__ float s_t[64][65];
  __shared__ float s_w[256][27];
  const int b = blockIdx.x, t = threadIdx.x;
  if (b < 32) {
    const float* src;
    bf16_t* dst;
    int kt, nt;
    if (b < 16) { src = vp_w; dst = vp_wF; kt = b >> 2; nt = b & 3; }
    else        { src = op_w; dst = op_wF; kt = (b - 16) >> 2; nt = (b - 16) & 3; }
    const int nl = t & 63, kh = t >> 6;
    const int n = nt * 64 + nl;
#pragma unroll
    for (int i = 0; i < 16; ++i) {
      const int kl = kh * 16 + i;
      s_t[kl][nl] = src[(size_t)(kt * 64 + kl) * CC + n];
    }
    __syncthreads();
    const int lane = t & 63, kq = lane >> 4, n15 = lane & 15, n16 = t >> 6;
#pragma unroll
    for (int it = 0; it < 2; ++it) {
      bf16x8 v;
#pragma unroll
      for (int j = 0; j < 8; ++j)
        v[j] = (bf16_t)s_t[it * 32 + kq * 8 + j][n16 * 16 + n15];
      const size_t off = (size_t)(nt * 4 + n16) * 4096 + (size_t)(kt * 2 + it) * 512 +
                         kq * 128 + n15 * 8;
      *(bf16x8*)(dst + off) = v;
    }
  } else {
    const int g = b - 32;
    // transpose load: s_w[c][j] = om_w[c][g*27+j]
#pragma unroll
    for (int j = 0; j < 27; ++j) s_w[t][j] = om_w[(size_t)t * 864 + g * 27 + j];
    __syncthreads();
#pragma unroll
    for (int i = 0; i < 4; ++i) {
      const int chunk = i * 256 + t;  // 1024 chunks of 8 bf16
      const int tile = chunk >> 9, ks = (chunk >> 6) & 7, kq = (chunk >> 4) & 3,
                n15 = chunk & 15;
      const int j = tile * 16 + n15;
      bf16x8 v;
#pragma unroll
      for (int cl = 0; cl < 8; ++cl) {
        const int c = ks * 32 + kq * 8 + cl;
        v[cl] = (j < 27) ? (bf16_t)s_w[c][j] : (bf16_t)0.0f;
      }
      *(bf16x8*)(om_wG + ((size_t)g << 13) + (size_t)chunk * 8) = v;
    }
  }
}

// ---------------- KF: fused dwconv3x3 + value GEMM; block = one image row ----
__global__ __launch_bounds__(512, 4) void dwconv_value_kernel(
    const float* __restrict__ x, const float* __restrict__ dw_w,
    const float* __restrict__ dw_b, const bf16_t* __restrict__ vp_wF,
    const float* __restrict__ vp_b, bf16_t* __restrict__ xdwF,
    bf16_t* __restrict__ value_g) {
  __shared__ bf16_t s_xf[64 * 256];  // x bf16 fragments for this row's 4 m-tiles

  const int t = threadIdx.x;
  const int row = blockIdx.x;        // img*64 + y
  const int y = row & 63;
  const int img = row >> 6;

  // ---- Phase A: dwconv
  {
    const int cq = (t & 63) * 4;   // channel base
    const int seg = t >> 6;        // 8-px segment
    const bool up = (y > 0), dn = (y < HH - 1);
    const float* xrow = x + (size_t)row * WW * CC + cq;

    const float4 bias = *(const float4*)&dw_b[cq];
    float4 dw[9];
#pragma unroll
    for (int i = 0; i < 9; ++i) dw[i] = *(const float4*)&dw_w[(size_t)i * CC + cq];

    const float4 zero = make_float4(0.f, 0.f, 0.f, 0.f);
    auto loadcol = [&](int xx, float4 c[3]) {
      if (xx < 0 || xx >= WW) { c[0] = c[1] = c[2] = zero; return; }
      c[0] = up ? *(const float4*)(xrow + ((size_t)xx - WW) * CC) : zero;
      c[1] = *(const float4*)(xrow + (size_t)xx * CC);
      c[2] = dn ? *(const float4*)(xrow + ((size_t)xx + WW) * CC) : zero;
    };

    const int x0 = seg * 8;
    float4 cm[3], cc[3], cp[3];
    loadcol(x0 - 1, cm);
    loadcol(x0, cc);

    for (int xx = x0; xx < x0 + 8; ++xx) {
      loadcol(xx + 1, cp);
      float4 a = bias;
#pragma unroll
      for (int r = 0; r < 3; ++r) {
        const float4 w0 = dw[r * 3 + 0], w1 = dw[r * 3 + 1], w2 = dw[r * 3 + 2];
        a.x = fmaf(cm[r].x, w0.x, fmaf(cc[r].x, w1.x, fmaf(cp[r].x, w2.x, a.x)));
        a.y = fmaf(cm[r].y, w0.y, fmaf(cc[r].y, w1.y, fmaf(cp[r].y, w2.y, a.y)));
        a.z = fmaf(cm[r].z, w0.z, fmaf(cc[r].z, w1.z, fmaf(cp[r].z, w2.z, a.z)));
        a.w = fmaf(cm[r].w, w0.w, fmaf(cc[r].w, w1.w, fmaf(cp[r].w, w2.w, a.w)));
      }
      const int pix = row * WW + xx;
      bf16x4 av, cv;
      av[0] = (bf16_t)a.x; av[1] = (bf16_t)a.y; av[2] = (bf16_t)a.z; av[3] = (bf16_t)a.w;
      cv[0] = (bf16_t)cc[1].x; cv[1] = (bf16_t)cc[1].y;
      cv[2] = (bf16_t)cc[1].z; cv[3] = (bf16_t)cc[1].w;
      *(bf16x4*)&xdwF[fragIdx(pix, cq)] = av;
      const int lf = (xx >> 4) * 4096 + ((cq >> 5) * 512) + (((cq >> 3) & 3) * 128) +
                     ((xx & 15) * 8) + (cq & 7);
      *(bf16x4*)&s_xf[lf] = cv;
#pragma unroll
      for (int r = 0; r < 3; ++r) { cm[r] = cc[r]; cc[r] = cp[r]; }
    }
  }
  __syncthreads();

  // ---- Phase B: value GEMM (M=64 from LDS, N=256)
  {
    const int lane = t & 63;
    const int wave = t >> 6;
    const int mq = wave >> 1;      // m-tile 0..3
    const int nh = wave & 1;       // n-half
    const int m = lane & 15;
    const int kq = lane >> 4;

    const bf16_t* Ap = s_xf + mq * 4096 + lane * 8;
    const bf16_t* Bp = vp_wF + (size_t)(nh * 8) * 4096 + lane * 8;

    f32x4 acc[8] = {};
#pragma unroll
    for (int ks = 0; ks < 8; ++ks) {
      const bf16x8 a = *(const bf16x8*)(Ap + ks * 512);
#pragma unroll
      for (int i = 0; i < 8; ++i) {
        const bf16x8 b = *(const bf16x8*)(Bp + (size_t)i * 4096 + ks * 512);
        acc[i] = __builtin_amdgcn_mfma_f32_16x16x32_bf16(a, b, acc[i], 0, 0, 0);
      }
    }

#pragma unroll
    for (int i = 0; i < 8; ++i) {
      const int n = (nh * 8 + i) * 16 + m;
      const float bs = vp_b[n];
      const int g = n >> 3, c = n & 7;
      bf16_t* plane = value_g + ((size_t)(img * G + g) << 15) + c;
#pragma unroll
      for (int r = 0; r < 4; ++r) {
        const int pl = mq * 16 + kq * 4 + r;           // pixel local 0..63
        const int pin = y * 64 + pl;                   // pixel within image
        plane[(size_t)pin * GC] = (bf16_t)(acc[i][r] + bs);
      }
    }
  }
}

// ---------------- OMS: fused om GEMM + sampling; block = (img, g, quarter) --
// grid b: img = b&7, g = (b>>3)&31, quarter = b>>8  (R9-proven config).
// Block = 512 threads = 8 waves; each wave owns 8 m-tiles (128 px).
// LDS 135.2 KB -> 1 block/CU. Sampling: 2 px/thread, scalar math (R15).
__global__ __launch_bounds__(512, 2) void oms_kernel(
    const bf16_t* __restrict__ xdwF, const bf16_t* __restrict__ om_wG,
    const float* __restrict__ om_b, const bf16_t* __restrict__ value_g,
    bf16_t* __restrict__ sampledF) {
  __shared__ bf16x8 s_v[66 * 66];          // 69,696 B zero-padded value plane
  __shared__ bf16_t s_om[8][4][128][8];    // 65,536 B chunk-major, p-stride 16B

  const int t = threadIdx.x;
  const int lane = t & 63, wave = t >> 6;  // wave 0..7
  const int b = blockIdx.x;
  const int img = b & 7, g = (b >> 3) & 31, quarter = b >> 8;
  const int c15 = lane & 15, kq = lane >> 4;
  const int tile0 = img * 256 + quarter * 64;   // global 16-px-tile base

  // ---- B-frags (g's padded 32 om columns) into registers
  bf16x8 wf[2][8];
  {
    const bf16_t* base = om_wG + ((size_t)g << 13) + (size_t)lane * 8;
#pragma unroll
    for (int n2 = 0; n2 < 2; ++n2)
#pragma unroll
      for (int ks = 0; ks < 8; ++ks)
        wf[n2][ks] = *(const bf16x8*)(base + n2 * 4096 + ks * 512);
  }
  float bias[2][4];
#pragma unroll
  for (int n2 = 0; n2 < 2; ++n2)
#pragma unroll
    for (int r = 0; r < 4; ++r) {
      const int j = n2 * 16 + kq * 4 + r;
      bias[n2][r] = (j < 27) ? om_b[g * 27 + j] : 0.0f;
    }

  // ---- stage full value plane: zero border + interior
  {
    const bf16x8 zv = {};
    for (int i = t; i < 260; i += 512) {
      int Y, X;
      if (i < 66)       { Y = 0;           X = i; }
      else if (i < 132) { Y = 65;          X = i - 66; }
      else if (i < 196) { Y = i - 132 + 1; X = 0; }
      else              { Y = i - 196 + 1; X = 65; }
      s_v[Y * 66 + X] = zv;
    }
    const bf16x8* plane = (const bf16x8*)(value_g + ((size_t)(img * G + g) << 15));
#pragma unroll
    for (int i = 0; i < 8; ++i) {
      const int c = i * 512 + t;   // 0..4095
      s_v[((c >> 6) + 1) * 66 + (c & 63) + 1] = plane[c];
    }
  }

  // ---- om GEMM: 8 tiles/wave -> s_om[wave] (D[j][px], bf16, chunk-major)
  {
    const int tb = tile0 + wave * 8;
#pragma unroll
    for (int q = 0; q < 8; ++q) {
      const bf16_t* Ap = xdwF + ((size_t)(tb + q)) * 4096 + (size_t)lane * 8;
      f32x4 a0 = {}, a1 = {};
#pragma unroll
      for (int ks = 0; ks < 8; ++ks) {
        const bf16x8 xf = *(const bf16x8*)(Ap + ks * 512);
        a0 = __builtin_amdgcn_mfma_f32_16x16x32_bf16(wf[0][ks], xf, a0, 0, 0, 0);
        a1 = __builtin_amdgcn_mfma_f32_16x16x32_bf16(wf[1][ks], xf, a1, 0, 0, 0);
      }
      // lane holds j = n2*16 + kq*4 + r for pixel p = q*16 + c15 (0..127)
      const int p = q * 16 + c15;
      bf16x4 b0, b1;
#pragma unroll
      for (int r = 0; r < 4; ++r) {
        b0[r] = (bf16_t)(a0[r] + bias[0][r]);
        b1[r] = (bf16_t)(a1[r] + bias[1][r]);
      }
      // chunk = j>>3: n2=0 -> kq>>1, n2=1 -> 2+(kq>>1); half = kq&1
      *(bf16x4*)&s_om[wave][kq >> 1][p][(kq & 1) * 4] = b0;
      *(bf16x4*)&s_om[wave][2 + (kq >> 1)][p][(kq & 1) * 4] = b1;
    }
  }
  __syncthreads();   // s_v ready (s_om is same-wave, covered by the barrier too)

  // ---- sampling: 2 px/thread (rows wave*2 and wave*2+1 of the quarter),
  //      interleaved tap chains, scalar cvt+fmaf (R15 form — fastest measured)
  {
    const int pinA = quarter * 1024 + wave * 128 + lane;  // in-image px
    const int pinB = pinA + 64;
    float arrA[27], arrB[27];
#pragma unroll
    for (int c = 0; c < 4; ++c) {
      const bf16x8 oA = *(const bf16x8*)&s_om[wave][c][lane][0];
      const bf16x8 oB = *(const bf16x8*)&s_om[wave][c][64 + lane][0];
#pragma unroll
      for (int j = 0; j < 8; ++j) {
        const int idx = c * 8 + j;
        if (idx < 27) { arrA[idx] = (float)oA[j]; arrB[idx] = (float)oB[j]; }
      }
    }
    const int xw = lane;             // pin & 63 (wave*128 is 0 mod 64)
    const int yA = (pinA >> 6) & 63;
    const int yB = yA + 1;

    float accA[GC], accB[GC];
#pragma unroll
    for (int c = 0; c < GC; ++c) { accA[c] = 0.0f; accB[c] = 0.0f; }

    auto tap = [&](const float* arr, const int y, float* acc, const int k) {
      const float pxf = (float)(xw + (k % 3) - 1) + arr[2 * k];
      const float pyf = (float)(y + (k / 3) - 1) + arr[2 * k + 1];
      const float mk = arr[18 + k];
      const float x0f = floorf(pxf), y0f = floorf(pyf);
      const float tx = pxf - x0f, ty = pyf - y0f;
      const int ix = (int)x0f, iy = (int)y0f;

      // clamp to padded range [-1,64]; border zeros kill OOB contributions
      const int iX0 = min(max(ix, -1), 64) + 1;
      const int iX1 = min(max(ix + 1, -1), 64) + 1;
      const int iY0 = min(max(iy, -1), 64) + 1;
      const int iY1 = min(max(iy + 1, -1), 64) + 1;

      const bf16x8 v00 = s_v[iY0 * 66 + iX0];
      const bf16x8 v01 = s_v[iY0 * 66 + iX1];
      const bf16x8 v10 = s_v[iY1 * 66 + iX0];
      const bf16x8 v11 = s_v[iY1 * 66 + iX1];

      const float w00 = mk * (1.0f - ty) * (1.0f - tx);
      const float w01 = mk * (1.0f - ty) * tx;
      const float w10 = mk * ty * (1.0f - tx);
      const float w11 = mk * ty * tx;

#pragma unroll
      for (int c = 0; c < GC; ++c) {
        float s = acc[c];
        s = fmaf(w00, (float)v00[c], s);
        s = fmaf(w01, (float)v01[c], s);
        s = fmaf(w10, (float)v10[c], s);
        s = fmaf(w11, (float)v11[c], s);
        acc[c] = s;
      }
    };

#pragma unroll
    for (int k = 0; k < 9; ++k) {
      tap(arrA, yA, accA, k);
      tap(arrB, yB, accB, k);
    }

    bf16x8 svA, svB;
#pragma unroll
    for (int c = 0; c < GC; ++c) {
      svA[c] = (bf16_t)accA[c];
      svB[c] = (bf16_t)accB[c];
    }
    *(bf16x8*)(sampledF + fragIdx(img * 4096 + pinA, g * 8)) = svA;
    *(bf16x8*)(sampledF + fragIdx(img * 4096 + pinB, g * 8)) = svB;
  }
}

// ---------------- K4: out = sampledF @ op_wF, M=128/block, B in LDS ----------
// Block = 1024 thr = 16 waves (mq 0..7, nh 0..1); full op_wF (128 KB) staged
// once into LDS; per wave 64 MFMA fed by conflict-free ds_read_b128 + 8
// global A-loads. Grid 256 = 1 block/CU.
__global__ __launch_bounds__(1024, 1) void out_gemm_kernel(
    const bf16_t* __restrict__ AF, const bf16_t* __restrict__ BF,
    float* __restrict__ out) {
  __shared__ bf16_t s_b[CC * CC];  // 131,072 B: full B, frag layout (linear copy)

  const int t = threadIdx.x;
  {
    const bf16x8* src = (const bf16x8*)BF;
    bf16x8* dst = (bf16x8*)s_b;
#pragma unroll
    for (int i = 0; i < 8; ++i) dst[i * 1024 + t] = src[i * 1024 + t];
  }
  __syncthreads();

  const int lane = t & 63;
  const int wave = t >> 6;        // 0..15
  const int mq = wave >> 1;       // m-tile 0..7
  const int nh = wave & 1;        // n-half
  const int mt = blockIdx.x * 8 + mq;
  const int m = lane & 15;
  const int kq = lane >> 4;

  const bf16_t* Ap = AF + (size_t)mt * 4096 + lane * 8;
  const bf16_t* Bp = s_b + (size_t)(nh * 8) * 4096 + lane * 8;

  f32x4 acc[8] = {};
#pragma unroll
  for (int ks = 0; ks < 8; ++ks) {
    const bf16x8 a = *(const bf16x8*)(Ap + ks * 512);
#pragma unroll
    for (int i = 0; i < 8; ++i) {
      const bf16x8 b = *(const bf16x8*)(Bp + (size_t)i * 4096 + ks * 512);
      acc[i] = __builtin_amdgcn_mfma_f32_16x16x32_bf16(a, b, acc[i], 0, 0, 0);
    }
  }

#pragma unroll
  for (int i = 0; i < 8; ++i) {
    const int n = (nh * 8 + i) * 16 + m;
#pragma unroll
    for (int r = 0; r < 4; ++r) {
      const int pix = mt * 16 + kq * 4 + r;
      out[(size_t)pix * CC + n] = acc[i][r];
    }
  }
}

extern "C" void kernel_launch(void* const* d_in, const int* in_sizes, int n_in,
                              void* d_out, int out_size, void* d_ws, size_t ws_size,
                              hipStream_t stream) {
  const float* x = (const float*)d_in[0];
  const float* dw_w = (const float*)d_in[1];
  const float* dw_b = (const float*)d_in[2];
  const float* om_w = (const float*)d_in[3];
  const float* om_b = (const float*)d_in[4];
  const float* vp_w = (const float*)d_in[5];
  const float* vp_b = (const float*)d_in[6];
  const float* op_w = (const float*)d_in[7];
  float* out = (float*)d_out;

  // workspace layout (bytes)
  char* ws = (char*)d_ws;
  bf16_t* value_g = (bf16_t*)ws;                      // 16,777,216
  bf16_t* xdwF = (bf16_t*)(ws + 16777216);            // 16,777,216
  bf16_t* sampledF = (bf16_t*)(ws + 33554432);        // 16,777,216
  bf16_t* om_wG = (bf16_t*)(ws + 50331648);           //    524,288
  bf16_t* vp_wF = (bf16_t*)(ws + 50855936);           //    131,072
  bf16_t* op_wF = (bf16_t*)(ws + 50987008);           //    131,072

  convert_weights_kernel<<<64, 256, 0, stream>>>(om_w, vp_w, op_w,
                                                 om_wG, vp_wF, op_wF);
  dwconv_value_kernel<<<NN * HH, 512, 0, stream>>>(x, dw_w, dw_b, vp_wF, vp_b,
                                                   xdwF, value_g);
  oms_kernel<<<1024, 512, 0, stream>>>(xdwF, om_wG, om_b, value_g, sampledF);
  out_gemm_kernel<<<NPIX / 128, 1024, 0, stream>>>(sampledF, op_wF, out);
}

// Round 13
// 188.101 us; speedup vs baseline: 1.1237x; 1.0305x over previous
//
#include <hip/hip_runtime.h>

// DCNv4 on gfx950 — bf16 MFMA pipeline, fragment-swizzled operands.
// R20: KF store-path fix (only kernel changed vs R19's 193.8us).
//  Evidence: top-5 all oms@57.8 -> KW/KF/K4 each <57.8 but sum to ~136us.
//  KF's epilogue = 8.4M scattered 2B value_g stores (R8's proven
//  store-bound anti-pattern) + 2M scattered 8B xdwF stores.
//  - Phase A: av -> s_xdw LDS (32KB, frag layout); cooperative linear
//    copy -> xdwF as coalesced 16B stores after barrier.
//  - Phase B epilogue: acc -> s_xf (dead post-MFMA) with (g+px)&31 chunk
//    rotation (read-side conflict-free at b128 floor); cooperative store
//    -> value_g as 1KB contiguous runs per g (chunk=g*64+px, lane=px).
//  LDS 64KB -> still 2 blocks/CU (grid gives 2/CU anyway).
// KW: vp/op frag-swizzle + per-g padded om_wG
// KF: dwconv3x3 + value GEMM (block = image row) -> xdwF, value_g
// OMS: om GEMM (B in regs) -> s_om -> 2-px scalar sampling -> sampledF
// K4: out = sampledF @ op_wF (M=128, B in LDS, fp32 NHWC out)

typedef __bf16 bf16_t;
typedef bf16_t bf16x8 __attribute__((ext_vector_type(8)));
typedef bf16_t bf16x4 __attribute__((ext_vector_type(4)));
typedef float f32x4 __attribute__((ext_vector_type(4)));

namespace {
constexpr int NN = 8, HH = 64, WW = 64, CC = 256;
constexpr int G = 32, GC = 8;
constexpr int NPIX = NN * HH * WW;            // 32768
}

// fragment-swizzled flat index for a [rows][256] bf16 matrix
__device__ __forceinline__ size_t fragIdx(int row, int c) {
  return ((size_t)(row >> 4) * 4096) + ((c >> 5) * 512) + (((c >> 3) & 3) * 128) +
         ((row & 15) * 8) + (c & 7);
}

// ---------------- KW: weights -> bf16 fragment layouts ----------------------
// b<16: vp_w  b<32: op_w  (64x64 LDS transpose, as before)
// b>=32: om_wG[g] = per-g fragment matrix [32 rows(j, 27 real)][256 cols(c)]
__global__ __launch_bounds__(256) void convert_weights_kernel(
    const float* __restrict__ om_w, const float* __restrict__ vp_w,
    const float* __restrict__ op_w, bf16_t* __restrict__ om_wG,
    bf16_t* __restrict__ vp_wF, bf16_t* __restrict__ op_wF) {
  __shared__ float s_t[64][65];
  __shared__ float s_w[256][27];
  const int b = blockIdx.x, t = threadIdx.x;
  if (b < 32) {
    const float* src;
    bf16_t* dst;
    int kt, nt;
    if (b < 16) { src = vp_w; dst = vp_wF; kt = b >> 2; nt = b & 3; }
    else        { src = op_w; dst = op_wF; kt = (b - 16) >> 2; nt = (b - 16) & 3; }
    const int nl = t & 63, kh = t >> 6;
    const int n = nt * 64 + nl;
#pragma unroll
    for (int i = 0; i < 16; ++i) {
      const int kl = kh * 16 + i;
      s_t[kl][nl] = src[(size_t)(kt * 64 + kl) * CC + n];
    }
    __syncthreads();
    const int lane = t & 63, kq = lane >> 4, n15 = lane & 15, n16 = t >> 6;
#pragma unroll
    for (int it = 0; it < 2; ++it) {
      bf16x8 v;
#pragma unroll
      for (int j = 0; j < 8; ++j)
        v[j] = (bf16_t)s_t[it * 32 + kq * 8 + j][n16 * 16 + n15];
      const size_t off = (size_t)(nt * 4 + n16) * 4096 + (size_t)(kt * 2 + it) * 512 +
                         kq * 128 + n15 * 8;
      *(bf16x8*)(dst + off) = v;
    }
  } else {
    const int g = b - 32;
    // transpose load: s_w[c][j] = om_w[c][g*27+j]
#pragma unroll
    for (int j = 0; j < 27; ++j) s_w[t][j] = om_w[(size_t)t * 864 + g * 27 + j];
    __syncthreads();
#pragma unroll
    for (int i = 0; i < 4; ++i) {
      const int chunk = i * 256 + t;  // 1024 chunks of 8 bf16
      const int tile = chunk >> 9, ks = (chunk >> 6) & 7, kq = (chunk >> 4) & 3,
                n15 = chunk & 15;
      const int j = tile * 16 + n15;
      bf16x8 v;
#pragma unroll
      for (int cl = 0; cl < 8; ++cl) {
        const int c = ks * 32 + kq * 8 + cl;
        v[cl] = (j < 27) ? (bf16_t)s_w[c][j] : (bf16_t)0.0f;
      }
      *(bf16x8*)(om_wG + ((size_t)g << 13) + (size_t)chunk * 8) = v;
    }
  }
}

// ---------------- KF: fused dwconv3x3 + value GEMM; block = one image row ----
__global__ __launch_bounds__(512, 2) void dwconv_value_kernel(
    const float* __restrict__ x, const float* __restrict__ dw_w,
    const float* __restrict__ dw_b, const bf16_t* __restrict__ vp_wF,
    const float* __restrict__ vp_b, bf16_t* __restrict__ xdwF,
    bf16_t* __restrict__ value_g) {
  __shared__ bf16_t s_xf[64 * 256];   // x bf16 frags; reused as rotated s_out
  __shared__ bf16_t s_xdw[64 * 256];  // xdw bf16 frags (staged, coalesced out)

  const int t = threadIdx.x;
  const int row = blockIdx.x;        // img*64 + y
  const int y = row & 63;
  const int img = row >> 6;

  // ---- Phase A: dwconv -> s_xdw (LDS only; no global stores)
  {
    const int cq = (t & 63) * 4;   // channel base
    const int seg = t >> 6;        // 8-px segment
    const bool up = (y > 0), dn = (y < HH - 1);
    const float* xrow = x + (size_t)row * WW * CC + cq;

    const float4 bias = *(const float4*)&dw_b[cq];
    float4 dw[9];
#pragma unroll
    for (int i = 0; i < 9; ++i) dw[i] = *(const float4*)&dw_w[(size_t)i * CC + cq];

    const float4 zero = make_float4(0.f, 0.f, 0.f, 0.f);
    auto loadcol = [&](int xx, float4 c[3]) {
      if (xx < 0 || xx >= WW) { c[0] = c[1] = c[2] = zero; return; }
      c[0] = up ? *(const float4*)(xrow + ((size_t)xx - WW) * CC) : zero;
      c[1] = *(const float4*)(xrow + (size_t)xx * CC);
      c[2] = dn ? *(const float4*)(xrow + ((size_t)xx + WW) * CC) : zero;
    };

    const int x0 = seg * 8;
    float4 cm[3], cc[3], cp[3];
    loadcol(x0 - 1, cm);
    loadcol(x0, cc);

    for (int xx = x0; xx < x0 + 8; ++xx) {
      loadcol(xx + 1, cp);
      float4 a = bias;
#pragma unroll
      for (int r = 0; r < 3; ++r) {
        const float4 w0 = dw[r * 3 + 0], w1 = dw[r * 3 + 1], w2 = dw[r * 3 + 2];
        a.x = fmaf(cm[r].x, w0.x, fmaf(cc[r].x, w1.x, fmaf(cp[r].x, w2.x, a.x)));
        a.y = fmaf(cm[r].y, w0.y, fmaf(cc[r].y, w1.y, fmaf(cp[r].y, w2.y, a.y)));
        a.z = fmaf(cm[r].z, w0.z, fmaf(cc[r].z, w1.z, fmaf(cp[r].z, w2.z, a.z)));
        a.w = fmaf(cm[r].w, w0.w, fmaf(cc[r].w, w1.w, fmaf(cp[r].w, w2.w, a.w)));
      }
      bf16x4 av, cv;
      av[0] = (bf16_t)a.x; av[1] = (bf16_t)a.y; av[2] = (bf16_t)a.z; av[3] = (bf16_t)a.w;
      cv[0] = (bf16_t)cc[1].x; cv[1] = (bf16_t)cc[1].y;
      cv[2] = (bf16_t)cc[1].z; cv[3] = (bf16_t)cc[1].w;
      const int lf = (xx >> 4) * 4096 + ((cq >> 5) * 512) + (((cq >> 3) & 3) * 128) +
                     ((xx & 15) * 8) + (cq & 7);
      *(bf16x4*)&s_xdw[lf] = av;
      *(bf16x4*)&s_xf[lf] = cv;
#pragma unroll
      for (int r = 0; r < 3; ++r) { cm[r] = cc[r]; cc[r] = cp[r]; }
    }
  }
  __syncthreads();

  // ---- cooperative coalesced xdwF store (2048 x 16B linear)
  {
    const bf16x8* src = (const bf16x8*)s_xdw;
    bf16x8* dst = (bf16x8*)(xdwF + (size_t)row * 16384);
#pragma unroll
    for (int i = 0; i < 4; ++i) {
      const int idx = i * 512 + t;
      dst[idx] = src[idx];
    }
  }

  // ---- Phase B: value GEMM (M=64 from LDS, N=256)
  {
    const int lane = t & 63;
    const int wave = t >> 6;
    const int mq = wave >> 1;      // m-tile 0..3
    const int nh = wave & 1;       // n-half
    const int m = lane & 15;
    const int kq = lane >> 4;

    const bf16_t* Ap = s_xf + mq * 4096 + lane * 8;
    const bf16_t* Bp = vp_wF + (size_t)(nh * 8) * 4096 + lane * 8;

    f32x4 acc[8] = {};
#pragma unroll
    for (int ks = 0; ks < 8; ++ks) {
      const bf16x8 a = *(const bf16x8*)(Ap + ks * 512);
#pragma unroll
      for (int i = 0; i < 8; ++i) {
        const bf16x8 b = *(const bf16x8*)(Bp + (size_t)i * 4096 + ks * 512);
        acc[i] = __builtin_amdgcn_mfma_f32_16x16x32_bf16(a, b, acc[i], 0, 0, 0);
      }
    }

    __syncthreads();   // all waves done reading s_xf; safe to overwrite

    // rotated staging: s_out[px][((g+px)&31)*8 + c] (read-side conflict-free)
    bf16_t* s_out = s_xf;
#pragma unroll
    for (int i = 0; i < 8; ++i) {
      const int n = (nh * 8 + i) * 16 + m;
      const float bs = vp_b[n];
      const int g = n >> 3, c = n & 7;
#pragma unroll
      for (int r = 0; r < 4; ++r) {
        const int pl = mq * 16 + kq * 4 + r;           // pixel local 0..63
        s_out[pl * 256 + (((g + pl) & 31) << 3) + c] = (bf16_t)(acc[i][r] + bs);
      }
    }
  }
  __syncthreads();

  // ---- cooperative coalesced value_g store: chunk = g*64+px -> 1KB runs/g
  {
    const bf16x8* s16 = (const bf16x8*)s_xf;
    bf16x8* dst = (bf16x8*)value_g;
#pragma unroll
    for (int i = 0; i < 4; ++i) {
      const int chunk = i * 512 + t;       // 0..2047
      const int g = chunk >> 6, px = chunk & 63;
      const bf16x8 v = s16[px * 32 + ((g + px) & 31)];
      dst[((size_t)(img * G + g) << 12) + y * 64 + px] = v;
    }
  }
}

// ---------------- OMS: fused om GEMM + sampling; block = (img, g, quarter) --
// grid b: img = b&7, g = (b>>3)&31, quarter = b>>8  (R9-proven config).
// Block = 512 threads = 8 waves; each wave owns 8 m-tiles (128 px).
// LDS 135.2 KB -> 1 block/CU. Sampling: 2 px/thread, scalar math (R15).
__global__ __launch_bounds__(512, 2) void oms_kernel(
    const bf16_t* __restrict__ xdwF, const bf16_t* __restrict__ om_wG,
    const float* __restrict__ om_b, const bf16_t* __restrict__ value_g,
    bf16_t* __restrict__ sampledF) {
  __shared__ bf16x8 s_v[66 * 66];          // 69,696 B zero-padded value plane
  __shared__ bf16_t s_om[8][4][128][8];    // 65,536 B chunk-major, p-stride 16B

  const int t = threadIdx.x;
  const int lane = t & 63, wave = t >> 6;  // wave 0..7
  const int b = blockIdx.x;
  const int img = b & 7, g = (b >> 3) & 31, quarter = b >> 8;
  const int c15 = lane & 15, kq = lane >> 4;
  const int tile0 = img * 256 + quarter * 64;   // global 16-px-tile base

  // ---- B-frags (g's padded 32 om columns) into registers
  bf16x8 wf[2][8];
  {
    const bf16_t* base = om_wG + ((size_t)g << 13) + (size_t)lane * 8;
#pragma unroll
    for (int n2 = 0; n2 < 2; ++n2)
#pragma unroll
      for (int ks = 0; ks < 8; ++ks)
        wf[n2][ks] = *(const bf16x8*)(base + n2 * 4096 + ks * 512);
  }
  float bias[2][4];
#pragma unroll
  for (int n2 = 0; n2 < 2; ++n2)
#pragma unroll
    for (int r = 0; r < 4; ++r) {
      const int j = n2 * 16 + kq * 4 + r;
      bias[n2][r] = (j < 27) ? om_b[g * 27 + j] : 0.0f;
    }

  // ---- stage full value plane: zero border + interior
  {
    const bf16x8 zv = {};
    for (int i = t; i < 260; i += 512) {
      int Y, X;
      if (i < 66)       { Y = 0;           X = i; }
      else if (i < 132) { Y = 65;          X = i - 66; }
      else if (i < 196) { Y = i - 132 + 1; X = 0; }
      else              { Y = i - 196 + 1; X = 65; }
      s_v[Y * 66 + X] = zv;
    }
    const bf16x8* plane = (const bf16x8*)(value_g + ((size_t)(img * G + g) << 15));
#pragma unroll
    for (int i = 0; i < 8; ++i) {
      const int c = i * 512 + t;   // 0..4095
      s_v[((c >> 6) + 1) * 66 + (c & 63) + 1] = plane[c];
    }
  }

  // ---- om GEMM: 8 tiles/wave -> s_om[wave] (D[j][px], bf16, chunk-major)
  {
    const int tb = tile0 + wave * 8;
#pragma unroll
    for (int q = 0; q < 8; ++q) {
      const bf16_t* Ap = xdwF + ((size_t)(tb + q)) * 4096 + (size_t)lane * 8;
      f32x4 a0 = {}, a1 = {};
#pragma unroll
      for (int ks = 0; ks < 8; ++ks) {
        const bf16x8 xf = *(const bf16x8*)(Ap + ks * 512);
        a0 = __builtin_amdgcn_mfma_f32_16x16x32_bf16(wf[0][ks], xf, a0, 0, 0, 0);
        a1 = __builtin_amdgcn_mfma_f32_16x16x32_bf16(wf[1][ks], xf, a1, 0, 0, 0);
      }
      // lane holds j = n2*16 + kq*4 + r for pixel p = q*16 + c15 (0..127)
      const int p = q * 16 + c15;
      bf16x4 b0, b1;
#pragma unroll
      for (int r = 0; r < 4; ++r) {
        b0[r] = (bf16_t)(a0[r] + bias[0][r]);
        b1[r] = (bf16_t)(a1[r] + bias[1][r]);
      }
      // chunk = j>>3: n2=0 -> kq>>1, n2=1 -> 2+(kq>>1); half = kq&1
      *(bf16x4*)&s_om[wave][kq >> 1][p][(kq & 1) * 4] = b0;
      *(bf16x4*)&s_om[wave][2 + (kq >> 1)][p][(kq & 1) * 4] = b1;
    }
  }
  __syncthreads();   // s_v ready (s_om is same-wave, covered by the barrier too)

  // ---- sampling: 2 px/thread (rows wave*2 and wave*2+1 of the quarter),
  //      interleaved tap chains, scalar cvt+fmaf (R15 form — fastest measured)
  {
    const int pinA = quarter * 1024 + wave * 128 + lane;  // in-image px
    const int pinB = pinA + 64;
    float arrA[27], arrB[27];
#pragma unroll
    for (int c = 0; c < 4; ++c) {
      const bf16x8 oA = *(const bf16x8*)&s_om[wave][c][lane][0];
      const bf16x8 oB = *(const bf16x8*)&s_om[wave][c][64 + lane][0];
#pragma unroll
      for (int j = 0; j < 8; ++j) {
        const int idx = c * 8 + j;
        if (idx < 27) { arrA[idx] = (float)oA[j]; arrB[idx] = (float)oB[j]; }
      }
    }
    const int xw = lane;             // pin & 63 (wave*128 is 0 mod 64)
    const int yA = (pinA >> 6) & 63;
    const int yB = yA + 1;

    float accA[GC], accB[GC];
#pragma unroll
    for (int c = 0; c < GC; ++c) { accA[c] = 0.0f; accB[c] = 0.0f; }

    auto tap = [&](const float* arr, const int y, float* acc, const int k) {
      const float pxf = (float)(xw + (k % 3) - 1) + arr[2 * k];
      const float pyf = (float)(y + (k / 3) - 1) + arr[2 * k + 1];
      const float mk = arr[18 + k];
      const float x0f = floorf(pxf), y0f = floorf(pyf);
      const float tx = pxf - x0f, ty = pyf - y0f;
      const int ix = (int)x0f, iy = (int)y0f;

      // clamp to padded range [-1,64]; border zeros kill OOB contributions
      const int iX0 = min(max(ix, -1), 64) + 1;
      const int iX1 = min(max(ix + 1, -1), 64) + 1;
      const int iY0 = min(max(iy, -1), 64) + 1;
      const int iY1 = min(max(iy + 1, -1), 64) + 1;

      const bf16x8 v00 = s_v[iY0 * 66 + iX0];
      const bf16x8 v01 = s_v[iY0 * 66 + iX1];
      const bf16x8 v10 = s_v[iY1 * 66 + iX0];
      const bf16x8 v11 = s_v[iY1 * 66 + iX1];

      const float w00 = mk * (1.0f - ty) * (1.0f - tx);
      const float w01 = mk * (1.0f - ty) * tx;
      const float w10 = mk * ty * (1.0f - tx);
      const float w11 = mk * ty * tx;

#pragma unroll
      for (int c = 0; c < GC; ++c) {
        float s = acc[c];
        s = fmaf(w00, (float)v00[c], s);
        s = fmaf(w01, (float)v01[c], s);
        s = fmaf(w10, (float)v10[c], s);
        s = fmaf(w11, (float)v11[c], s);
        acc[c] = s;
      }
    };

#pragma unroll
    for (int k = 0; k < 9; ++k) {
      tap(arrA, yA, accA, k);
      tap(arrB, yB, accB, k);
    }

    bf16x8 svA, svB;
#pragma unroll
    for (int c = 0; c < GC; ++c) {
      svA[c] = (bf16_t)accA[c];
      svB[c] = (bf16_t)accB[c];
    }
    *(bf16x8*)(sampledF + fragIdx(img * 4096 + pinA, g * 8)) = svA;
    *(bf16x8*)(sampledF + fragIdx(img * 4096 + pinB, g * 8)) = svB;
  }
}

// ---------------- K4: out = sampledF @ op_wF, M=128/block, B in LDS ----------
// Block = 1024 thr = 16 waves (mq 0..7, nh 0..1); full op_wF (128 KB) staged
// once into LDS; per wave 64 MFMA fed by conflict-free ds_read_b128 + 8
// global A-loads. Grid 256 = 1 block/CU.
__global__ __launch_bounds__(1024, 1) void out_gemm_kernel(
    const bf16_t* __restrict__ AF, const bf16_t* __restrict__ BF,
    float* __restrict__ out) {
  __shared__ bf16_t s_b[CC * CC];  // 131,072 B: full B, frag layout (linear copy)

  const int t = threadIdx.x;
  {
    const bf16x8* src = (const bf16x8*)BF;
    bf16x8* dst = (bf16x8*)s_b;
#pragma unroll
    for (int i = 0; i < 8; ++i) dst[i * 1024 + t] = src[i * 1024 + t];
  }
  __syncthreads();

  const int lane = t & 63;
  const int wave = t >> 6;        // 0..15
  const int mq = wave >> 1;       // m-tile 0..7
  const int nh = wave & 1;        // n-half
  const int mt = blockIdx.x * 8 + mq;
  const int m = lane & 15;
  const int kq = lane >> 4;

  const bf16_t* Ap = AF + (size_t)mt * 4096 + lane * 8;
  const bf16_t* Bp = s_b + (size_t)(nh * 8) * 4096 + lane * 8;

  f32x4 acc[8] = {};
#pragma unroll
  for (int ks = 0; ks < 8; ++ks) {
    const bf16x8 a = *(const bf16x8*)(Ap + ks * 512);
#pragma unroll
    for (int i = 0; i < 8; ++i) {
      const bf16x8 b = *(const bf16x8*)(Bp + (size_t)i * 4096 + ks * 512);
      acc[i] = __builtin_amdgcn_mfma_f32_16x16x32_bf16(a, b, acc[i], 0, 0, 0);
    }
  }

#pragma unroll
  for (int i = 0; i < 8; ++i) {
    const int n = (nh * 8 + i) * 16 + m;
#pragma unroll
    for (int r = 0; r < 4; ++r) {
      const int pix = mt * 16 + kq * 4 + r;
      out[(size_t)pix * CC + n] = acc[i][r];
    }
  }
}

extern "C" void kernel_launch(void* const* d_in, const int* in_sizes, int n_in,
                              void* d_out, int out_size, void* d_ws, size_t ws_size,
                              hipStream_t stream) {
  const float* x = (const float*)d_in[0];
  const float* dw_w = (const float*)d_in[1];
  const float* dw_b = (const float*)d_in[2];
  const float* om_w = (const float*)d_in[3];
  const float* om_b = (const float*)d_in[4];
  const float* vp_w = (const float*)d_in[5];
  const float* vp_b = (const float*)d_in[6];
  const float* op_w = (const float*)d_in[7];
  float* out = (float*)d_out;

  // workspace layout (bytes)
  char* ws = (char*)d_ws;
  bf16_t* value_g = (bf16_t*)ws;                      // 16,777,216
  bf16_t* xdwF = (bf16_t*)(ws + 16777216);            // 16,777,216
  bf16_t* sampledF = (bf16_t*)(ws + 33554432);        // 16,777,216
  bf16_t* om_wG = (bf16_t*)(ws + 50331648);           //    524,288
  bf16_t* vp_wF = (bf16_t*)(ws + 50855936);           //    131,072
  bf16_t* op_wF = (bf16_t*)(ws + 50987008);           //    131,072

  convert_weights_kernel<<<64, 256, 0, stream>>>(om_w, vp_w, op_w,
                                                 om_wG, vp_wF, op_wF);
  dwconv_value_kernel<<<NN * HH, 512, 0, stream>>>(x, dw_w, dw_b, vp_wF, vp_b,
                                                   xdwF, value_g);
  oms_kernel<<<1024, 512, 0, stream>>>(xdwF, om_wG, om_b, value_g, sampledF);
  out_gemm_kernel<<<NPIX / 128, 1024, 0, stream>>>(sampledF, op_wF, out);
}